// Round 3
// baseline (321.666 us; speedup 1.0000x reference)
//
#include <hip/hip_runtime.h>
#include <hip/hip_bf16.h>

#define D_MODEL 256
#define LQ 4800
#define NB 2
#define MROWS (NB * LQ)       // 9600
#define LN_EPS 1e-5f
#define CH 16                 // attn keys per chunk

typedef unsigned int u32;
typedef unsigned short u16;
typedef __attribute__((ext_vector_type(8))) short bf16x8;
typedef __attribute__((ext_vector_type(4))) float f32x4;

__device__ __forceinline__ float bf2f(u32 bits16) {
    return __uint_as_float(bits16 << 16);
}
__device__ __forceinline__ u16 f2bf(float f) {
    __hip_bfloat16 h = __float2bfloat16(f);
    return *reinterpret_cast<u16*>(&h);
}

// ---------------------------------------------------------------------------
// Fused prep: cast x & source to bf16; transpose+cast all weights.
// grid: [0,2400) cast x, [2400,4800) cast source, [4800,7360) weight tiles.
// ---------------------------------------------------------------------------
__global__ __launch_bounds__(256) void prep_kernel(
    const float* __restrict__ x, const float* __restrict__ source,
    const float* __restrict__ Wq, const float* __restrict__ Wk,
    const float* __restrict__ Wv, const float* __restrict__ Wm,
    const float* __restrict__ W1, const float* __restrict__ W2,
    u16* __restrict__ xb, u16* __restrict__ sb,
    u16* __restrict__ Wqt, u16* __restrict__ Wkvt, u16* __restrict__ Wmt,
    u16* __restrict__ W1t, u16* __restrict__ W2t)
{
    __shared__ float tile[16][17];
    const int t = threadIdx.x;
    int bid = blockIdx.x;

    if (bid < 4800) {
        const float* src = bid < 2400 ? x : source;
        u16* dst = bid < 2400 ? xb : sb;
        int b = bid < 2400 ? bid : bid - 2400;
        int i = (b * 256 + t) * 4;
        float4 v = *reinterpret_cast<const float4*>(src + i);
        ushort4 o; o.x = f2bf(v.x); o.y = f2bf(v.y); o.z = f2bf(v.z); o.w = f2bf(v.w);
        *reinterpret_cast<ushort4*>(dst + i) = o;
        return;
    }
    int sub = bid - 4800;
    const float* W; u16* Wt; int Nd, ldt, rowoff;
    if      (sub < 256)  { W = Wq; Wt = Wqt;  Nd = 256; ldt = 256; rowoff = 0;   }
    else if (sub < 512)  { W = Wk; Wt = Wkvt; Nd = 256; ldt = 256; rowoff = 0;   sub -= 256; }
    else if (sub < 768)  { W = Wv; Wt = Wkvt; Nd = 256; ldt = 256; rowoff = 256; sub -= 512; }
    else if (sub < 1024) { W = Wm; Wt = Wmt;  Nd = 256; ldt = 256; rowoff = 0;   sub -= 768; }
    else if (sub < 2048) { W = W1; Wt = W1t;  Nd = 512; ldt = 512; rowoff = 0;   sub -= 1024; }
    else                 { W = W2; Wt = W2t;  Nd = 256; ldt = 512; rowoff = 0;   sub -= 2048; }
    int ntiles = Nd >> 4;
    int tn = sub % ntiles, tk = sub / ntiles;
    int tx = t & 15, ty = t >> 4;
    tile[ty][tx] = W[(size_t)(tk * 16 + ty) * Nd + tn * 16 + tx];
    __syncthreads();
    Wt[(size_t)(rowoff + tn * 16 + ty) * ldt + tk * 16 + tx] = f2bf(tile[tx][ty]);
}

// ---------------------------------------------------------------------------
// bf16 MFMA GEMM (unchanged from round 2): C[M,N] = act(A[M,K] @ Bt[N,K]^T)
// 128x128 tile, BK=32, 256 threads. flags: 1 = relu, 2 = bf16 output.
// ---------------------------------------------------------------------------
__global__ __launch_bounds__(256) void gemm_mfma_kernel(
    const u16* __restrict__ A0, int lda0,
    const u16* __restrict__ A1, int lda1, int splitK,
    const u16* __restrict__ Bt, int ldb,
    void* __restrict__ Cout,
    int M, int N, int K, int flags)
{
    __shared__ __align__(16) u16 As[128 * 32];
    __shared__ __align__(16) u16 Bs[128 * 32];

    const int t  = threadIdx.x;
    const int l  = t & 63;
    const int w  = t >> 6;
    const int m0 = blockIdx.y * 128;
    const int n0 = blockIdx.x * 128;
    const int wr = w >> 1, wc = w & 1;

    const int srow = l >> 2;
    const int sch  = (l & 3) ^ (srow & 3);

    f32x4 acc[4][4];
#pragma unroll
    for (int i = 0; i < 4; ++i)
#pragma unroll
        for (int j = 0; j < 4; ++j) acc[i][j] = (f32x4){0.f, 0.f, 0.f, 0.f};

    for (int k0 = 0; k0 < K; k0 += 32) {
        const u16* Ap; int kk, lda;
        if (splitK && k0 >= splitK) { Ap = A1; kk = k0 - splitK; lda = lda1; }
        else                        { Ap = A0; kk = k0;          lda = lda0; }

#pragma unroll
        for (int g = 0; g < 2; ++g) {
            int grp = w * 2 + g;
            int row = grp * 16 + srow;
            const u16* asrc = Ap + (size_t)(m0 + row) * lda + kk + sch * 8;
            u32* adst = (u32*)(As + grp * 512);
            __builtin_amdgcn_global_load_lds(
                (const __attribute__((address_space(1))) u32*)asrc,
                (__attribute__((address_space(3))) u32*)adst, 16, 0, 0);
            const u16* bsrc = Bt + (size_t)(n0 + row) * ldb + k0 + sch * 8;
            u32* bdst = (u32*)(Bs + grp * 512);
            __builtin_amdgcn_global_load_lds(
                (const __attribute__((address_space(1))) u32*)bsrc,
                (__attribute__((address_space(3))) u32*)bdst, 16, 0, 0);
        }
        __syncthreads();

        const int r  = l & 15;
        const int ch = l >> 4;
        bf16x8 af[4], bfr[4];
#pragma unroll
        for (int i = 0; i < 4; ++i) {
            int ar = wr * 64 + i * 16 + r;
            af[i] = *(const bf16x8*)((const char*)As + ar * 64 + ((ch ^ (r & 3)) * 16));
        }
#pragma unroll
        for (int j = 0; j < 4; ++j) {
            int br = wc * 64 + j * 16 + r;
            bfr[j] = *(const bf16x8*)((const char*)Bs + br * 64 + ((ch ^ (r & 3)) * 16));
        }
#pragma unroll
        for (int i = 0; i < 4; ++i)
#pragma unroll
            for (int j = 0; j < 4; ++j)
                acc[i][j] = __builtin_amdgcn_mfma_f32_16x16x32_bf16(af[i], bfr[j], acc[i][j], 0, 0, 0);
        __syncthreads();
    }

    const int r  = l & 15;
    const int q4 = l >> 4;
#pragma unroll
    for (int i = 0; i < 4; ++i)
#pragma unroll
        for (int j = 0; j < 4; ++j) {
            int col = n0 + wc * 64 + j * 16 + r;
#pragma unroll
            for (int reg = 0; reg < 4; ++reg) {
                int row = m0 + wr * 64 + i * 16 + q4 * 4 + reg;
                float vv = acc[i][j][reg];
                if (flags & 1) vv = fmaxf(vv, 0.f);
                if (flags & 2) ((u16*)Cout)[(size_t)row * N + col] = f2bf(vv);
                else           ((float*)Cout)[(size_t)row * N + col] = vv;
            }
        }
}

// ---------------------------------------------------------------------------
// Gathered attention, flash-style, fused K|V rows.
// q: [MROWS][256] bf16. kvmat: [MROWS][512] bf16 (K|V). idx: [MROWS][64].
// One 256-thread block per query; 4 chunks of 16 keys; online softmax;
// XOR-swizzled LDS (slot ^= row&7) on both write and read sides.
// ---------------------------------------------------------------------------
__global__ __launch_bounds__(256) void attn_kernel(
    const u16* __restrict__ q, const u16* __restrict__ kvmat,
    const int* __restrict__ idx, u16* __restrict__ msg)
{
    __shared__ u32 q_u[128];
    __shared__ u32 kv_u[2 * CH * 128];   // [area][row][128 dwords] = 16 KB
    __shared__ int idx_s[64];

    const int t  = threadIdx.x;
    const int qi = blockIdx.x;
    const int n  = qi / LQ;
    const u16* kvb = kvmat + (size_t)n * LQ * 512;

    if (t < 64) idx_s[t] = idx[(size_t)qi * 64 + t];
    if (t < 32) ((uint4*)q_u)[t] = ((const uint4*)(q + (size_t)qi * 256))[t];
    __syncthreads();

    // staging roles
    const int sr   = t >> 4;        // row-in-chunk 0..15
    const int area = (t >> 3) & 1;  // 0=K, 1=V
    const int seg  = t & 7;         // 64B segment within area-row
    // score roles
    const int h  = t >> 5;          // head 0..7
    const int kl = (t >> 1) & 15;   // key 0..15
    const int ds = t & 1;           // d-half
    // PV roles
    const int d  = t & 31;

    // unpack this thread's q slice once: elems [h*32+ds*16, +16)
    float qf[16];
    {
        const u32* qp = q_u + h * 16 + ds * 8;
#pragma unroll
        for (int p = 0; p < 8; ++p) {
            u32 wv = qp[p];
            qf[2 * p]     = bf2f(wv & 0xffff);
            qf[2 * p + 1] = bf2f(wv >> 16);
        }
    }

    uint4 bufA[4], bufB[4];
    auto g_issue = [&](int c, uint4* bb) {
        int row = idx_s[c * CH + sr];
        const uint4* src = (const uint4*)(kvb + (size_t)row * 512 + area * 256 + seg * 32);
#pragma unroll
        for (int u = 0; u < 4; ++u) bb[u] = src[u];
    };
    auto stage = [&](const uint4* bb) {
#pragma unroll
        for (int u = 0; u < 4; ++u) {
            int s  = seg * 4 + u;
            int sp = (s & 24) | ((s ^ sr) & 7);
            *(uint4*)(kv_u + area * 2048 + sr * 128 + sp * 4) = bb[u];
        }
    };

    float m_run = -3.0e38f, l_run = 0.f, macc = 0.f;
    const float scale = 0.17677669529663687f;

    auto chunk_compute = [&]() {
        // ---- scores: thread (h,kl,ds) does a 16-wide partial dot ----
        int bs  = h * 4 + ds * 2;
        int sp0 = (bs & 24) | ((bs ^ kl) & 7);
        int sp1 = ((bs + 1) & 24) | (((bs + 1) ^ kl) & 7);
        uint4 k0 = *(const uint4*)(kv_u + kl * 128 + sp0 * 4);
        uint4 k1 = *(const uint4*)(kv_u + kl * 128 + sp1 * 4);
        float acc = 0.f;
        const u32 kw[8] = {k0.x, k0.y, k0.z, k0.w, k1.x, k1.y, k1.z, k1.w};
#pragma unroll
        for (int p = 0; p < 8; ++p) {
            acc = fmaf(bf2f(kw[p] & 0xffff), qf[2 * p],     acc);
            acc = fmaf(bf2f(kw[p] >> 16),    qf[2 * p + 1], acc);
        }
        acc += __shfl_xor(acc, 1);        // combine d-halves
        float s = acc * scale;
        // ---- online softmax within the 32-lane head group ----
        float mc = s;
#pragma unroll
        for (int off = 2; off <= 16; off <<= 1) mc = fmaxf(mc, __shfl_xor(mc, off, 32));
        float m_new = fmaxf(m_run, mc);
        float p_    = __expf(s - m_new);
        float alpha = __expf(m_run - m_new);
        float contrib = ds ? 0.f : p_;
#pragma unroll
        for (int off = 1; off <= 16; off <<= 1) contrib += __shfl_xor(contrib, off, 32);
        l_run = l_run * alpha + contrib;
        m_run = m_new;
        // ---- PV: thread (h,d) accumulates msg[h*32+d] ----
        macc *= alpha;
        const int sl = h * 4 + (d >> 3);
#pragma unroll
        for (int i = 0; i < CH; ++i) {
            float pi = __shfl(p_, i * 2, 32);
            int sp = (sl & 24) | ((sl ^ i) & 7);
            u32 wv = kv_u[2048 + i * 128 + sp * 4 + ((d >> 1) & 3)];
            float vv = bf2f((d & 1) ? (wv >> 16) : (wv & 0xffff));
            macc = fmaf(pi, vv, macc);
        }
    };

    g_issue(0, bufA);
    stage(bufA); g_issue(1, bufB);
    __syncthreads();
    chunk_compute();
    __syncthreads();
    stage(bufB); g_issue(2, bufA);
    __syncthreads();
    chunk_compute();
    __syncthreads();
    stage(bufA); g_issue(3, bufB);
    __syncthreads();
    chunk_compute();
    __syncthreads();
    stage(bufB);
    __syncthreads();
    chunk_compute();

    msg[(size_t)qi * 256 + t] = f2bf(macc / l_run);
}

// ---------------------------------------------------------------------------
// LayerNorm over last dim (256), fp32 input. One block per row.
// ---------------------------------------------------------------------------
__global__ __launch_bounds__(256) void ln_kernel(
    const float* __restrict__ in, const float* __restrict__ g,
    const float* __restrict__ b, const float* __restrict__ xadd,
    void* __restrict__ out, int out_bf16)
{
    __shared__ float red[8];
    const int t = threadIdx.x;
    const size_t row = blockIdx.x;
    float val = in[row * 256 + t];

    float s = val;
#pragma unroll
    for (int off = 32; off; off >>= 1) s += __shfl_down(s, off, 64);
    if ((t & 63) == 0) red[t >> 6] = s;
    __syncthreads();
    float mu = (red[0] + red[1] + red[2] + red[3]) * 0.00390625f;

    float dv = val - mu;
    float s2 = dv * dv;
#pragma unroll
    for (int off = 32; off; off >>= 1) s2 += __shfl_down(s2, off, 64);
    if ((t & 63) == 0) red[4 + (t >> 6)] = s2;
    __syncthreads();
    float var = (red[4] + red[5] + red[6] + red[7]) * 0.00390625f;
    float rstd = rsqrtf(var + LN_EPS);

    float r = dv * rstd * g[t] + b[t];
    if (xadd) r += xadd[row * 256 + t];
    if (out_bf16) ((u16*)out)[row * 256 + t] = f2bf(r);
    else          ((float*)out)[row * 256 + t] = r;
}

// ---------------------------------------------------------------------------
extern "C" void kernel_launch(void* const* d_in, const int* in_sizes, int n_in,
                              void* d_out, int out_size, void* d_ws, size_t ws_size,
                              hipStream_t stream)
{
    const float* x      = (const float*)d_in[0];
    const float* source = (const float*)d_in[1];
    const int*   eidx   = (const int*)d_in[2];
    const float* Wq     = (const float*)d_in[3];
    const float* Wk     = (const float*)d_in[4];
    const float* Wv     = (const float*)d_in[5];
    const float* Wm     = (const float*)d_in[6];
    const float* W1     = (const float*)d_in[7];
    const float* W2     = (const float*)d_in[8];
    const float* g1     = (const float*)d_in[9];
    const float* b1     = (const float*)d_in[10];
    const float* g2     = (const float*)d_in[11];
    const float* b2     = (const float*)d_in[12];
    float* out = (float*)d_out;

    char* ws = (char*)d_ws;
    const size_t SZB = (size_t)MROWS * 256 * 2;    // 4.9 MB
    u16* xb     = (u16*)(ws);                      // live until W1 gemm
    u16* sb     = (u16*)(ws + SZB);                // dead after kv gemm
    u16* qb     = (u16*)(ws + 2 * SZB);            // dead after attn
    u16* kvb    = (u16*)(ws + 3 * SZB);            // [9600][512], dead after attn
    u16* msgb   = (u16*)(ws + 5 * SZB);            // dead after Wm gemm
    float* msgW = (float*)(ws + SZB);              // overlays sb+qb (dead)
    u16* msglnb = (u16*)(ws + 3 * SZB);            // overlays kvb low half (dead)
    u16* h1b    = (u16*)(ws + 4 * SZB);            // [9600][512], overlays kvb hi + msgb
    float* h2   = (float*)(ws + SZB);              // overlays msgW (dead)
    u16* Wqt    = (u16*)(ws + 6 * SZB);
    u16* Wkvt   = Wqt + 256 * 256;                 // [512][256]
    u16* Wmt    = Wkvt + 512 * 256;
    u16* W1t    = Wmt + 256 * 256;                 // [512][512]
    u16* W2t    = W1t + 512 * 512;                 // [256][512]

    dim3 blk(256);

    // one fused prep launch: casts + all weight transposes
    prep_kernel<<<dim3(7360), blk, 0, stream>>>(x, source, Wq, Wk, Wv, Wm, W1, W2,
                                                xb, sb, Wqt, Wkvt, Wmt, W1t, W2t);

    // q projection; fused k|v projection
    gemm_mfma_kernel<<<dim3(2, 75), blk, 0, stream>>>(xb, 256, nullptr, 0, 0, Wqt, 256, qb, MROWS, 256, 256, 2);
    gemm_mfma_kernel<<<dim3(4, 75), blk, 0, stream>>>(sb, 256, nullptr, 0, 0, Wkvt, 256, kvb, MROWS, 512, 256, 2);

    // gathered attention -> msg (bf16)
    attn_kernel<<<dim3(MROWS), blk, 0, stream>>>(qb, kvb, eidx, msgb);

    // msg @ Wm -> fp32
    gemm_mfma_kernel<<<dim3(2, 75), blk, 0, stream>>>(msgb, 256, nullptr, 0, 0, Wmt, 256, msgW, MROWS, 256, 256, 0);

    // LN1 -> bf16
    ln_kernel<<<dim3(MROWS), blk, 0, stream>>>(msgW, g1, b1, nullptr, msglnb, 1);

    // concat(x, msgln) @ W1, relu -> bf16 [9600,512]
    gemm_mfma_kernel<<<dim3(4, 75), blk, 0, stream>>>(xb, 256, msglnb, 256, 256, W1t, 512, h1b, MROWS, 512, 512, 1 | 2);

    // h1 @ W2 -> fp32
    gemm_mfma_kernel<<<dim3(2, 75), blk, 0, stream>>>(h1b, 512, nullptr, 0, 0, W2t, 512, h2, MROWS, 256, 512, 0);

    // out = x + LN2(h2)
    ln_kernel<<<dim3(MROWS), blk, 0, stream>>>(h2, g2, b2, x, out, 0);
}

// Round 4
// 159.877 us; speedup vs baseline: 2.0120x; 2.0120x over previous
//
#include <hip/hip_runtime.h>
#include <hip/hip_bf16.h>

#define D_MODEL 256
#define LQ 4800
#define NB 2
#define MROWS (NB * LQ)       // 9600
#define LN_EPS 1e-5f

typedef unsigned int u32;
typedef unsigned short u16;
typedef __attribute__((ext_vector_type(8))) short bf16x8;
typedef __attribute__((ext_vector_type(4))) float f32x4;

__device__ __forceinline__ float bf2f(u32 bits16) {
    return __uint_as_float(bits16 << 16);
}
__device__ __forceinline__ u16 f2bf(float f) {
    __hip_bfloat16 h = __float2bfloat16(f);
    return *reinterpret_cast<u16*>(&h);
}

// ---------------------------------------------------------------------------
// Fused prep: cast x & source to bf16; transpose+cast all weights.
// grid: [0,2400) cast x, [2400,4800) cast source, [4800,7360) weight tiles.
// Wqkvt is [768][256]: rows 0..255 Wq^T, 256..511 Wk^T, 512..767 Wv^T.
// ---------------------------------------------------------------------------
__global__ __launch_bounds__(256) void prep_kernel(
    const float* __restrict__ x, const float* __restrict__ source,
    const float* __restrict__ Wq, const float* __restrict__ Wk,
    const float* __restrict__ Wv, const float* __restrict__ Wm,
    const float* __restrict__ W1, const float* __restrict__ W2,
    u16* __restrict__ xb, u16* __restrict__ sb,
    u16* __restrict__ Wqkvt, u16* __restrict__ Wmt,
    u16* __restrict__ W1t, u16* __restrict__ W2t)
{
    __shared__ float tile[16][17];
    const int t = threadIdx.x;
    int bid = blockIdx.x;

    if (bid < 4800) {
        const float* src = bid < 2400 ? x : source;
        u16* dst = bid < 2400 ? xb : sb;
        int b = bid < 2400 ? bid : bid - 2400;
        int i = (b * 256 + t) * 4;
        float4 v = *reinterpret_cast<const float4*>(src + i);
        ushort4 o; o.x = f2bf(v.x); o.y = f2bf(v.y); o.z = f2bf(v.z); o.w = f2bf(v.w);
        *reinterpret_cast<ushort4*>(dst + i) = o;
        return;
    }
    int sub = bid - 4800;
    const float* W; u16* Wt; int Nd, ldt, rowoff;
    if      (sub < 256)  { W = Wq; Wt = Wqkvt; Nd = 256; ldt = 256; rowoff = 0;   }
    else if (sub < 512)  { W = Wk; Wt = Wqkvt; Nd = 256; ldt = 256; rowoff = 256; sub -= 256; }
    else if (sub < 768)  { W = Wv; Wt = Wqkvt; Nd = 256; ldt = 256; rowoff = 512; sub -= 512; }
    else if (sub < 1024) { W = Wm; Wt = Wmt;   Nd = 256; ldt = 256; rowoff = 0;   sub -= 768; }
    else if (sub < 2048) { W = W1; Wt = W1t;   Nd = 512; ldt = 512; rowoff = 0;   sub -= 1024; }
    else                 { W = W2; Wt = W2t;   Nd = 256; ldt = 512; rowoff = 0;   sub -= 2048; }
    int ntiles = Nd >> 4;
    int tn = sub % ntiles, tk = sub / ntiles;
    int tx = t & 15, ty = t >> 4;
    tile[ty][tx] = W[(size_t)(tk * 16 + ty) * Nd + tn * 16 + tx];
    __syncthreads();
    Wt[(size_t)(rowoff + tn * 16 + ty) * ldt + tk * 16 + tx] = f2bf(tile[tx][ty]);
}

// ---------------------------------------------------------------------------
// bf16 MFMA GEMM: C = act(A @ Bt^T). 128x128 tile, BK=32, 256 threads.
// splitK: A = concat(A0 cols<splitK, A1 cols>=splitK) along K.
// nsel:   blocks with n0>=nsel use A1 as the whole A (qkv fusion).
// flags: 1=relu, 2=bf16 out, 4=route output to 3 consecutive [M,256] buffers
//        by col>>8 (qkv split).
// ---------------------------------------------------------------------------
__global__ __launch_bounds__(256) void gemm_mfma_kernel(
    const u16* __restrict__ A0, int lda0,
    const u16* __restrict__ A1, int lda1, int splitK, int nsel,
    const u16* __restrict__ Bt, int ldb,
    void* __restrict__ Cout,
    int M, int N, int K, int flags)
{
    __shared__ __align__(16) u16 As[128 * 32];
    __shared__ __align__(16) u16 Bs[128 * 32];

    const int t  = threadIdx.x;
    const int l  = t & 63;
    const int w  = t >> 6;
    const int m0 = blockIdx.y * 128;
    const int n0 = blockIdx.x * 128;
    const int wr = w >> 1, wc = w & 1;

    if (nsel && n0 >= nsel) { A0 = A1; lda0 = lda1; }

    const int srow = l >> 2;
    const int sch  = (l & 3) ^ (srow & 3);

    f32x4 acc[4][4];
#pragma unroll
    for (int i = 0; i < 4; ++i)
#pragma unroll
        for (int j = 0; j < 4; ++j) acc[i][j] = (f32x4){0.f, 0.f, 0.f, 0.f};

    for (int k0 = 0; k0 < K; k0 += 32) {
        const u16* Ap; int kk, lda;
        if (splitK && k0 >= splitK) { Ap = A1; kk = k0 - splitK; lda = lda1; }
        else                        { Ap = A0; kk = k0;          lda = lda0; }

#pragma unroll
        for (int g = 0; g < 2; ++g) {
            int grp = w * 2 + g;
            int row = grp * 16 + srow;
            const u16* asrc = Ap + (size_t)(m0 + row) * lda + kk + sch * 8;
            u32* adst = (u32*)(As + grp * 512);
            __builtin_amdgcn_global_load_lds(
                (const __attribute__((address_space(1))) u32*)asrc,
                (__attribute__((address_space(3))) u32*)adst, 16, 0, 0);
            const u16* bsrc = Bt + (size_t)(n0 + row) * ldb + k0 + sch * 8;
            u32* bdst = (u32*)(Bs + grp * 512);
            __builtin_amdgcn_global_load_lds(
                (const __attribute__((address_space(1))) u32*)bsrc,
                (__attribute__((address_space(3))) u32*)bdst, 16, 0, 0);
        }
        __syncthreads();

        const int r  = l & 15;
        const int ch = l >> 4;
        bf16x8 af[4], bfr[4];
#pragma unroll
        for (int i = 0; i < 4; ++i) {
            int ar = wr * 64 + i * 16 + r;
            af[i] = *(const bf16x8*)((const char*)As + ar * 64 + ((ch ^ (r & 3)) * 16));
        }
#pragma unroll
        for (int j = 0; j < 4; ++j) {
            int br = wc * 64 + j * 16 + r;
            bfr[j] = *(const bf16x8*)((const char*)Bs + br * 64 + ((ch ^ (r & 3)) * 16));
        }
#pragma unroll
        for (int i = 0; i < 4; ++i)
#pragma unroll
            for (int j = 0; j < 4; ++j)
                acc[i][j] = __builtin_amdgcn_mfma_f32_16x16x32_bf16(af[i], bfr[j], acc[i][j], 0, 0, 0);
        __syncthreads();
    }

    const int r  = l & 15;
    const int q4 = l >> 4;
#pragma unroll
    for (int i = 0; i < 4; ++i)
#pragma unroll
        for (int j = 0; j < 4; ++j) {
            int col = n0 + wc * 64 + j * 16 + r;
#pragma unroll
            for (int reg = 0; reg < 4; ++reg) {
                int row = m0 + wr * 64 + i * 16 + q4 * 4 + reg;
                float vv = acc[i][j][reg];
                if (flags & 1) vv = fmaxf(vv, 0.f);
                size_t off;
                int colw, Nw;
                if (flags & 4) { off = (size_t)(col >> 8) * M * 256; colw = col & 255; Nw = 256; }
                else           { off = 0; colw = col; Nw = N; }
                if (flags & 2) ((u16*)Cout)[off + (size_t)row * Nw + colw] = f2bf(vv);
                else           ((float*)Cout)[off + (size_t)row * Nw + colw] = vv;
            }
        }
}

// ---------------------------------------------------------------------------
// Gathered attention (round-1 proven structure + front-loaded gather loads).
// q,k,v: [MROWS,256] bf16 head-major. idx: [MROWS,64]. msg: [MROWS,256] bf16.
// One 256-thread block per query. All K/V gather loads issued to registers
// up front (T14 async-stage); 4 LDS phases do only ds_write + compute.
// ---------------------------------------------------------------------------
__global__ __launch_bounds__(256) void attn_kernel(
    const u16* __restrict__ q, const u16* __restrict__ k,
    const u16* __restrict__ v, const int* __restrict__ idx,
    u16* __restrict__ msg)
{
    __shared__ float q_s[256];
    __shared__ u32   kv_u[32 * 130];
    __shared__ float sc_s[8 * 64];

    const int t  = threadIdx.x;
    const int qi = blockIdx.x;
    const int n  = qi / LQ;
    const u16* kb = k + (size_t)n * LQ * 256;
    const u16* vb = v + (size_t)n * LQ * 256;

    const int sr = t >> 3;      // staging row 0..31
    const int sg = t & 7;       // 64B segment

    // gather row indices (8 lanes share each -> broadcast loads)
    int row0 = idx[(size_t)qi * 64 + sr];
    int row1 = idx[(size_t)qi * 64 + 32 + sr];

    q_s[t] = bf2f(q[(size_t)qi * 256 + t]);

    // issue K0, K1, V0 immediately (V1 later to cap register pressure)
    uint4 B0[4], B1[4], B2[4], B3[4];
    {
        const uint4* p0 = (const uint4*)(kb + (size_t)row0 * 256 + sg * 32);
        const uint4* p1 = (const uint4*)(kb + (size_t)row1 * 256 + sg * 32);
        const uint4* p2 = (const uint4*)(vb + (size_t)row0 * 256 + sg * 32);
#pragma unroll
        for (int u = 0; u < 4; ++u) B0[u] = p0[u];
#pragma unroll
        for (int u = 0; u < 4; ++u) B1[u] = p1[u];
#pragma unroll
        for (int u = 0; u < 4; ++u) B2[u] = p2[u];
    }

    const int h  = t >> 5;   // head 0..7
    const int kl = t & 31;   // key index within chunk
    const int d  = t & 31;   // output dim within head

    auto stage = [&](const uint4* bb) {
        u32* dp = kv_u + sr * 130 + sg * 16;
#pragma unroll
        for (int u = 0; u < 4; ++u) {
            ((uint2*)dp)[2 * u]     = make_uint2(bb[u].x, bb[u].y);
            ((uint2*)dp)[2 * u + 1] = make_uint2(bb[u].z, bb[u].w);
        }
    };
    auto score = [&](int c) {
        float acc = 0.f;
        const uint2* kr = (const uint2*)(kv_u + kl * 130 + h * 16);
        const float* qs = &q_s[h * 32];
#pragma unroll
        for (int p = 0; p < 8; ++p) {
            uint2 wv = kr[p];
            acc = fmaf(bf2f(wv.x & 0xffff), qs[4 * p + 0], acc);
            acc = fmaf(bf2f(wv.x >> 16),    qs[4 * p + 1], acc);
            acc = fmaf(bf2f(wv.y & 0xffff), qs[4 * p + 2], acc);
            acc = fmaf(bf2f(wv.y >> 16),    qs[4 * p + 3], acc);
        }
        sc_s[h * 64 + c * 32 + kl] = acc * 0.17677669529663687f;
    };

    float macc = 0.f;
    auto pv = [&](int c) {
#pragma unroll
        for (int i = 0; i < 32; ++i) {
            u32 wv = kv_u[i * 130 + h * 16 + (d >> 1)];
            float vv = bf2f((d & 1) ? (wv >> 16) : (wv & 0xffff));
            macc = fmaf(sc_s[h * 64 + c * 32 + i], vv, macc);
        }
    };

    // ---- phases: only ds_write + compute between barriers ----
    stage(B0);
    __syncthreads();           // q_s + K0 staged
    score(0);
    __syncthreads();
    stage(B1);
    __syncthreads();
    score(1);

    // softmax over 64 keys per head (thread (h,kl) owns its two slots)
    {
        float s0 = sc_s[h * 64 + kl];
        float s1 = sc_s[h * 64 + 32 + kl];
        float m = fmaxf(s0, s1);
#pragma unroll
        for (int off = 16; off; off >>= 1) m = fmaxf(m, __shfl_xor(m, off, 32));
        float e0 = expf(s0 - m);
        float e1 = expf(s1 - m);
        float sum = e0 + e1;
#pragma unroll
        for (int off = 16; off; off >>= 1) sum += __shfl_xor(sum, off, 32);
        float inv = 1.f / sum;
        sc_s[h * 64 + kl]      = e0 * inv;
        sc_s[h * 64 + 32 + kl] = e1 * inv;
    }
    __syncthreads();           // sc_s visible + kv_u reusable
    stage(B2);
    {   // issue V1 now; latency hides under pv(0)
        const uint4* p3 = (const uint4*)(vb + (size_t)row1 * 256 + sg * 32);
#pragma unroll
        for (int u = 0; u < 4; ++u) B3[u] = p3[u];
    }
    __syncthreads();
    pv(0);
    __syncthreads();
    stage(B3);
    __syncthreads();
    pv(1);

    msg[(size_t)qi * 256 + t] = f2bf(macc);
}

// ---------------------------------------------------------------------------
// LayerNorm over last dim (256), fp32 input. One block per row.
// ---------------------------------------------------------------------------
__global__ __launch_bounds__(256) void ln_kernel(
    const float* __restrict__ in, const float* __restrict__ g,
    const float* __restrict__ b, const float* __restrict__ xadd,
    void* __restrict__ out, int out_bf16)
{
    __shared__ float red[8];
    const int t = threadIdx.x;
    const size_t row = blockIdx.x;
    float val = in[row * 256 + t];

    float s = val;
#pragma unroll
    for (int off = 32; off; off >>= 1) s += __shfl_down(s, off, 64);
    if ((t & 63) == 0) red[t >> 6] = s;
    __syncthreads();
    float mu = (red[0] + red[1] + red[2] + red[3]) * 0.00390625f;

    float dv = val - mu;
    float s2 = dv * dv;
#pragma unroll
    for (int off = 32; off; off >>= 1) s2 += __shfl_down(s2, off, 64);
    if ((t & 63) == 0) red[4 + (t >> 6)] = s2;
    __syncthreads();
    float var = (red[4] + red[5] + red[6] + red[7]) * 0.00390625f;
    float rstd = rsqrtf(var + LN_EPS);

    float r = dv * rstd * g[t] + b[t];
    if (xadd) r += xadd[row * 256 + t];
    if (out_bf16) ((u16*)out)[row * 256 + t] = f2bf(r);
    else          ((float*)out)[row * 256 + t] = r;
}

// ---------------------------------------------------------------------------
extern "C" void kernel_launch(void* const* d_in, const int* in_sizes, int n_in,
                              void* d_out, int out_size, void* d_ws, size_t ws_size,
                              hipStream_t stream)
{
    const float* x      = (const float*)d_in[0];
    const float* source = (const float*)d_in[1];
    const int*   eidx   = (const int*)d_in[2];
    const float* Wq     = (const float*)d_in[3];
    const float* Wk     = (const float*)d_in[4];
    const float* Wv     = (const float*)d_in[5];
    const float* Wm     = (const float*)d_in[6];
    const float* W1     = (const float*)d_in[7];
    const float* W2     = (const float*)d_in[8];
    const float* g1     = (const float*)d_in[9];
    const float* b1     = (const float*)d_in[10];
    const float* g2     = (const float*)d_in[11];
    const float* b2     = (const float*)d_in[12];
    float* out = (float*)d_out;

    char* ws = (char*)d_ws;
    const size_t SZB = (size_t)MROWS * 256 * 2;    // 4.9 MB
    u16* xb     = (u16*)(ws);                      // live until W1 gemm
    u16* sb     = (u16*)(ws + SZB);                // dead after qkv gemm
    u16* qb     = (u16*)(ws + 2 * SZB);            // qkv gemm routes here (seg 0)
    u16* kb     = (u16*)(ws + 3 * SZB);            // seg 1
    u16* vb     = (u16*)(ws + 4 * SZB);            // seg 2
    u16* msgb   = (u16*)(ws + 5 * SZB);            // dead after Wm gemm
    float* msgW = (float*)(ws + SZB);              // overlays sb+qb (dead)
    u16* msglnb = (u16*)(ws + 3 * SZB);            // overlays kb (dead)
    u16* h1b    = (u16*)(ws + 4 * SZB);            // [9600][512] overlays vb+msgb
    float* h2   = (float*)(ws + SZB);              // overlays msgW (dead)
    u16* Wqkvt  = (u16*)(ws + 6 * SZB);            // [768][256]
    u16* Wmt    = Wqkvt + 768 * 256;
    u16* W1t    = Wmt + 256 * 256;                 // [512][512]
    u16* W2t    = W1t + 512 * 512;                 // [256][512]

    dim3 blk(256);

    // fused prep: casts + all weight transposes
    prep_kernel<<<dim3(7360), blk, 0, stream>>>(x, source, Wq, Wk, Wv, Wm, W1, W2,
                                                xb, sb, Wqkvt, Wmt, W1t, W2t);

    // fused q|k|v projection (A = xb for cols<256, sb for cols>=256)
    gemm_mfma_kernel<<<dim3(6, 75), blk, 0, stream>>>(xb, 256, sb, 256, 0, 256,
                                                      Wqkvt, 256, qb, MROWS, 768, 256, 2 | 4);

    // gathered attention -> msg (bf16)
    attn_kernel<<<dim3(MROWS), blk, 0, stream>>>(qb, kb, vb, eidx, msgb);

    // msg @ Wm -> fp32
    gemm_mfma_kernel<<<dim3(2, 75), blk, 0, stream>>>(msgb, 256, nullptr, 0, 0, 0,
                                                      Wmt, 256, msgW, MROWS, 256, 256, 0);

    // LN1 -> bf16
    ln_kernel<<<dim3(MROWS), blk, 0, stream>>>(msgW, g1, b1, nullptr, msglnb, 1);

    // concat(x, msgln) @ W1, relu -> bf16 [9600,512]
    gemm_mfma_kernel<<<dim3(4, 75), blk, 0, stream>>>(xb, 256, msglnb, 256, 256, 0,
                                                      W1t, 512, h1b, MROWS, 512, 512, 1 | 2);

    // h1 @ W2 -> fp32
    gemm_mfma_kernel<<<dim3(2, 75), blk, 0, stream>>>(h1b, 512, nullptr, 0, 0, 0,
                                                      W2t, 512, h2, MROWS, 256, 512, 0);

    // out = x + LN2(h2)
    ln_kernel<<<dim3(MROWS), blk, 0, stream>>>(h2, g2, b2, x, out, 0);
}